// Round 7
// baseline (354.861 us; speedup 1.0000x reference)
//
#include <hip/hip_runtime.h>

// CRF Viterbi forward decode — R9: LDS-free state broadcast via v_readlane.
// potentials: [1024, 512, 48] f32, transition: [48, 48] f32.
// out = backpointers [1024, 511, 48] (float-encoded) ++ scores [1024, 48] f32.
//
// Measured history: R6 fused+shadow = 205 us dispatch (965 cyc/step).
// R8 in-step argmax = 228 us (1071 cyc/step) — parallel argmax was MORE
// issue (120 vs 94 insts) and VGPR=76 shows cross-barrier live ranges made
// the allocator rematerialize. R5 phase1 (NO argmax) = ~127 us = 596
// cyc/step vs ~160 modeled -> the skeleton itself carries ~400 cyc/step of
// structural cost: the LDS round trip (ds_write -> wave_barrier -> 12x
// ds_read -> first use) sits on the serial chain with 1 wave/SIMD and
// nothing hides it.
//
// R9 removes the LDS round trip: the state vector lives one-per-lane in
// myst; broadcast = 48 x v_readlane into SGPRs (values are wave-uniform),
// and cand[i] = s[i] + tcol[i] is v_add_f32 v,s,v (1 free SGPR operand).
// No LDS, no barrier, no sv[] regs, no cross-barrier live ranges. Step is
// pure register dataflow: readlane -> add -> max3 tree -> eq+min3 tree ->
// store; critical path ~30 cyc; issue-bound ~250 insts/step.
//
// Block = 1 wave, 48 lanes, lane j = destination tag; 1 block per batch.
// Stores/loads use offset-immediate addressing from per-chunk walking
// pointers (offsets <= 2112 B < 4096 limit). Prefetch guarded by one
// uniform branch (t0 < 506) instead of per-load clamp math. Rotating bp
// store-data regs kept (reg redefined 6 steps after its store -> no
// vmcnt WAR stall).

constexpr int B_ = 1024;
constexpr int T_ = 512;
constexpr int K_ = 48;
constexpr int C_ = 6;   // steps t=2..511 -> 510 = 6 * 85, no remainder

__device__ __forceinline__ int min3i(int a, int b, int c) {
    int m = a < b ? a : b;
    return m < c ? m : c;   // -> v_min3_i32
}

__global__ __launch_bounds__(64, 1)
__attribute__((amdgpu_waves_per_eu(1, 1)))
void crf_viterbi_kernel(
    const float* __restrict__ pot,
    const float* __restrict__ trans,
    float* __restrict__ out)
{
    const int b = blockIdx.x;
    const int j = threadIdx.x;  // 0..47 = destination tag

    // Transition column j -> 48 VGPRs (reused 511 times).
    float tcol[K_];
    #pragma unroll
    for (int i = 0; i < K_; ++i) tcol[i] = trans[i * K_ + j];

    const float* pp = pot + (size_t)b * T_ * K_ + j;
    float* bpp      = out + (size_t)b * (T_ - 1) * K_ + j;   // walking bp ptr
    float* scout    = out + (size_t)B_ * (T_ - 1) * K_ + (size_t)b * K_ + j;

    // t = 0 state (lane j holds S[j]).
    float myst = pp[0];

    // Rotating bp store-data registers: slot u redefined only 6 steps after
    // its store -> no per-step vmcnt store-ack WAR stall.
    float bpf0 = 0.0f, bpf1 = 0.0f, bpf2 = 0.0f,
          bpf3 = 0.0f, bpf4 = 0.0f, bpf5 = 0.0f;

// One step t: broadcast S(t-1) from lanes to SGPRs via readlane, cand,
// max3 value tree, eq+min3 first-occurrence argmax, bp row (t-1) store at
// offset-immediate UOFF*192 from bpp, state update. No LDS, no barrier.
#define STEP(PCUR, UOFF, BPV)                                                  \
    do {                                                                       \
        /* (1) Broadcast: 48 x v_readlane -> SGPRs (uniform values). */        \
        float s[K_];                                                           \
        _Pragma("unroll")                                                      \
        for (int i = 0; i < K_; ++i)                                           \
            s[i] = __int_as_float(                                             \
                __builtin_amdgcn_readlane(__float_as_int(myst), i));           \
        /* (2) 48 candidates: v_add_f32 v, s, v. */                            \
        float cand[K_];                                                        \
        _Pragma("unroll")                                                      \
        for (int i = 0; i < K_; ++i) cand[i] = s[i] + tcol[i];                 \
        /* (3) Value max: ternary tree -> v_max3_f32, 24 ops, depth 4. */      \
        float m1[16];                                                          \
        _Pragma("unroll")                                                      \
        for (int k = 0; k < 16; ++k)                                           \
            m1[k] = fmaxf(fmaxf(cand[3 * k], cand[3 * k + 1]), cand[3 * k + 2]); \
        float m2[6];                                                           \
        _Pragma("unroll")                                                      \
        for (int k = 0; k < 5; ++k)                                            \
            m2[k] = fmaxf(fmaxf(m1[3 * k], m1[3 * k + 1]), m1[3 * k + 2]);     \
        m2[5] = m1[15];                                                        \
        float mm = fmaxf(fmaxf(fmaxf(m2[0], m2[1]), m2[2]),                    \
                         fmaxf(fmaxf(m2[3], m2[4]), m2[5]));                   \
        /* (4) First-occurrence argmax: e[i] = eq ? i : 63 (inline consts),    \
           then v_min3_i32 tree. Exact: mm from same adds; min index among     \
           exact-equal = first occurrence, matches jnp.argmax. */              \
        int e[K_];                                                             \
        _Pragma("unroll")                                                      \
        for (int i = 0; i < K_; ++i) e[i] = (cand[i] == mm) ? i : 63;          \
        int n1[16];                                                            \
        _Pragma("unroll")                                                      \
        for (int k = 0; k < 16; ++k)                                           \
            n1[k] = min3i(e[3 * k], e[3 * k + 1], e[3 * k + 2]);               \
        int n2[6];                                                             \
        _Pragma("unroll")                                                      \
        for (int k = 0; k < 5; ++k)                                            \
            n2[k] = min3i(n1[3 * k], n1[3 * k + 1], n1[3 * k + 2]);            \
        n2[5] = n1[15];                                                        \
        int n30 = min3i(n2[0], n2[1], n2[2]);                                  \
        int n31 = min3i(n2[3], n2[4], n2[5]);                                  \
        int xx = n30 < n31 ? n30 : n31;                                        \
        BPV = (float)xx;                                                       \
        bpp[(UOFF) * K_] = BPV;   /* bp row t-1, offset-immediate store */     \
        /* (5) State update (pure register; next step readlanes it). */        \
        myst = (PCUR) + mm;                                                    \
    } while (0)

    // Potential for t=1 and prefetch t=2..7.
    float p1 = pp[(size_t)1 * K_];
    float pbuf[C_];
    #pragma unroll
    for (int u = 0; u < C_; ++u) pbuf[u] = pp[(size_t)(2 + u) * K_];
    const float* pld = pp + (size_t)8 * K_;   // next prefetch target (t=8)

    // t = 1: stores bp row 0 at offset 0, then advance past row 0.
    STEP(p1, 0, bpf5);
    bpp += K_;

    for (int t0 = 2; t0 < T_; t0 += C_) {   // t0 = 2, 8, ..., 506 (85 chunks)
        float pc[C_];
        #pragma unroll
        for (int u = 0; u < C_; ++u) pc[u] = pbuf[u];

        // Prefetch t0+6 .. t0+11 (offset-immediates from pld), except for
        // the final chunk (t0=506 would read t=512..517, OOB). Uniform
        // branch; pbuf stays stale-unused on the last chunk.
        if (t0 < T_ - C_) {
            #pragma unroll
            for (int u = 0; u < C_; ++u) pbuf[u] = pld[(size_t)u * K_];
            pld += (size_t)C_ * K_;
        }

        // Steps t0..t0+5 store bp rows t0-1..t0+4 at offsets 0..5 from bpp.
        STEP(pc[0], 0, bpf0);
        STEP(pc[1], 1, bpf1);
        STEP(pc[2], 2, bpf2);
        STEP(pc[3], 3, bpf3);
        STEP(pc[4], 4, bpf4);
        STEP(pc[5], 5, bpf5);
        bpp += (size_t)C_ * K_;
    }

    // Keep rotating store regs live (defeat DSE of the rotation).
    asm volatile("" :: "v"(bpf0), "v"(bpf1), "v"(bpf2),
                       "v"(bpf3), "v"(bpf4), "v"(bpf5));

    // Final Viterbi scores (S(511)).
    *scout = myst;
#undef STEP
}

extern "C" void kernel_launch(void* const* d_in, const int* in_sizes, int n_in,
                              void* d_out, int out_size, void* d_ws, size_t ws_size,
                              hipStream_t stream) {
    const float* pot   = (const float*)d_in[0];
    const float* trans = (const float*)d_in[1];
    float* out         = (float*)d_out;
    crf_viterbi_kernel<<<dim3(B_), dim3(K_), 0, stream>>>(pot, trans, out);
}